// Round 10
// baseline (299.700 us; speedup 1.0000x reference)
//
#include <hip/hip_runtime.h>

typedef __bf16 bf16;
typedef __bf16 bf16x8 __attribute__((ext_vector_type(8)));
typedef __bf16 bf16x4 __attribute__((ext_vector_type(4)));
typedef float floatx4 __attribute__((ext_vector_type(4)));
typedef float floatx16 __attribute__((ext_vector_type(16)));
typedef unsigned int uint4t __attribute__((ext_vector_type(4)));

typedef __attribute__((address_space(1))) void gvoid;
typedef __attribute__((address_space(3))) void lvoid;
#define ASYNC_COPY16(gp, lp) \
  __builtin_amdgcn_global_load_lds((gvoid*)(gp), (lvoid*)(lp), 16, 0, 0)

#define NB 4
#define SQ 2048
#define DMODEL 1024
#define NH 16
#define HD 64
#define MTOK (NB * SQ)   // 8192
#define LOG2E 1.44269504088896f

// workspace layout (bytes)
#define XB_OFF 0ull                        // bf16 X       [8192][1024]  16 MB
#define WT_OFF (16ull * 1024 * 1024)       // bf16 W^T x3  [3][1024][1024] 6 MB
#define Q_OFF  (22ull * 1024 * 1024)       // bf16 Q [64][2048][64]  16 MB (pre-scaled 0.125*log2e)
#define K_OFF  (38ull * 1024 * 1024)       // bf16 K [64][2048][64]  16 MB
#define V_OFF  (54ull * 1024 * 1024)       // bf16 V^T [64][64][2048] 16 MB
#define FLG_OFF (70ull * 1024 * 1024)      // int flags [4][16][32]   8 KB

// ------------------------------------------------- prep: convert X + transpose W + mask scan
__global__ __launch_bounds__(256) void prep(
    const float* __restrict__ x, bf16* __restrict__ xb,
    const float* __restrict__ w0, const float* __restrict__ w1,
    const float* __restrict__ w2, bf16* __restrict__ wt,
    const float* __restrict__ mask, int* __restrict__ flags) {
  __shared__ float tlds[32][33];
  int blk = blockIdx.x;
  int t = threadIdx.x;
  if (blk < 1024) {
    // X: 8192x1024 f32 -> bf16. 8 float4/thread, coalesced.
    size_t base = (size_t)blk * 2048 + t;
    const float4* xin = (const float4*)x;
    bf16x4* xo = (bf16x4*)xb;
#pragma unroll
    for (int j = 0; j < 8; j++) {
      float4 v = xin[base + j * 256];
      bf16x4 o;
      o[0] = (bf16)v.x; o[1] = (bf16)v.y; o[2] = (bf16)v.z; o[3] = (bf16)v.w;
      xo[base + j * 256] = o;
    }
  } else if (blk < 4096) {
    int tidx = blk - 1024;            // 0..3071
    int z = tidx >> 10;               // 0..2
    int rem = tidx & 1023;
    int kb = ((rem >> 5) & 31) * 32, nb = (rem & 31) * 32;
    const float* w = (z == 0) ? w0 : (z == 1) ? w1 : w2;
    bf16* out = wt + (size_t)z * DMODEL * DMODEL;
    int tx = t & 31, ty = t >> 5;     // 32 x 8
#pragma unroll
    for (int i = 0; i < 4; i++)
      tlds[ty + 8 * i][tx] = w[(size_t)(kb + ty + 8 * i) * DMODEL + nb + tx];
    __syncthreads();
#pragma unroll
    for (int i = 0; i < 4; i++)
      out[(size_t)(nb + ty + 8 * i) * DMODEL + kb + tx] = (bf16)tlds[tx][ty + 8 * i];
  } else {
    int midx = blk - 4096;            // 0..2047
    int kt = midx & 31, qt = (midx >> 5) & 15, b = midx >> 9;
    const float* mb = mask + ((size_t)b * SQ + qt * 128) * SQ + kt * 64;
    int row = t >> 1, half = t & 1;
    const float4* p = (const float4*)(mb + (size_t)row * SQ + half * 32);
    bool nz = false;
#pragma unroll
    for (int i = 0; i < 8; i++) {
      float4 vv = p[i];
      nz |= (vv.x != 0.f) | (vv.y != 0.f) | (vv.z != 0.f) | (vv.w != 0.f);
    }
    int* acc = (int*)tlds;
    if (t == 0) acc[0] = 0;
    __syncthreads();
    unsigned long long m = __ballot(nz);
    if ((t & 63) == 0 && m) atomicOr(acc, 1);
    __syncthreads();
    if (t == 0) flags[(b * 16 + qt) * 32 + kt] = acc[0];
  }
}

// ---------------------------------------------------------------- QKV GEMM (pure)
// 1536 blocks = 64 mt x 24 nt; XCD band mapping (id&7 -> mt band) for L2 reuse.
#define BK 64
__global__ __launch_bounds__(256) void qkv(
    const bf16* __restrict__ xb,   // [8192][1024]
    const bf16* __restrict__ wt,   // [3][1024 n][1024 k]
    const float* __restrict__ biasq, const float* __restrict__ biask,
    const float* __restrict__ biasv,
    bf16* __restrict__ q, bf16* __restrict__ k, bf16* __restrict__ v) {
  __shared__ bf16 smem[2 * 128 * BK];   // As | Bs, reused as [128][128] epilogue stage
  bf16* As = smem;
  bf16* Bs = smem + 128 * BK;

  int id = blockIdx.x;              // 0..1535
  int local = id >> 3;              // 0..191
  int mt = ((id & 7) << 3) | (local & 7);  // 0..63, band per XCD
  int nt = local >> 3;              // 0..23
  int t = threadIdx.x;

  int mat = nt >> 3;                // 0=Q 1=K 2=V
  int nbase = (nt & 7) * 128;
  const bf16* wmat = wt + (size_t)mat * DMODEL * DMODEL;
  const float* bias = (mat == 0) ? biasq : (mat == 1) ? biask : biasv;
  bf16* outp = (mat == 0) ? q : (mat == 1) ? k : v;

  int lane = t & 63, wid = t >> 6;
  int quad = lane >> 4, l16 = lane & 15;
  int wm = (wid & 1) * 64, wn = (wid >> 1) * 64;
  int xq = quad ^ (l16 & 7);        // swizzled chunk index

  floatx4 acc[4][4] = {};

  for (int kb = 0; kb < DMODEL; kb += BK) {
    __syncthreads();
#pragma unroll
    for (int p = 0; p < 4; p++) {
      int i2 = p * 256 + t;
      int row = i2 >> 3;
      int gch = (i2 ^ row) & 7;
      ASYNC_COPY16(xb + (size_t)(mt * 128 + row) * DMODEL + kb + gch * 8,
                   As + i2 * 8);
      ASYNC_COPY16(wmat + (size_t)(nbase + row) * DMODEL + kb + gch * 8,
                   Bs + i2 * 8);
    }
    __syncthreads();

#pragma unroll
    for (int kc = 0; kc < BK; kc += 32) {
      int xc = (kc >> 3) ^ xq;
      bf16x8 af[4], bfr[4];
#pragma unroll
      for (int mi = 0; mi < 4; mi++)
        af[mi] = *(const bf16x8*)(As + (wm + mi * 16 + l16) * BK + xc * 8);
#pragma unroll
      for (int ni = 0; ni < 4; ni++)
        bfr[ni] = *(const bf16x8*)(Bs + (wn + ni * 16 + l16) * BK + xc * 8);
      if (mat < 2) {   // transposed: D[n][m], col=l16=token
#pragma unroll
        for (int mi = 0; mi < 4; mi++)
#pragma unroll
          for (int ni = 0; ni < 4; ni++)
            acc[mi][ni] = __builtin_amdgcn_mfma_f32_16x16x32_bf16(
                bfr[ni], af[mi], acc[mi][ni], 0, 0, 0);
      } else {         // normal: D[m][n], col=l16=feature
#pragma unroll
        for (int mi = 0; mi < 4; mi++)
#pragma unroll
          for (int ni = 0; ni < 4; ni++)
            acc[mi][ni] = __builtin_amdgcn_mfma_f32_16x16x32_bf16(
                af[mi], bfr[ni], acc[mi][ni], 0, 0, 0);
      }
    }
  }

  int mg0 = mt * 128 + wm;
  if (mat < 2) {
    // Q/K: stage [s 128][n 128] tile in LDS (16B-unit swizzle), coalesced out.
    float qscale = (mat == 0) ? 0.125f * LOG2E : 1.0f;
    __syncthreads();                    // all waves done reading As/Bs
#pragma unroll
    for (int ni = 0; ni < 4; ni++) {
      int n0 = nbase + wn + ni * 16 + quad * 4;
      float4 bv4 = *(const float4*)(bias + n0);
      int nc = wn + ni * 16 + quad * 4;           // 0..127 in-tile n
      int unit = nc >> 3, h8 = (nc >> 2) & 1;
#pragma unroll
      for (int mi = 0; mi < 4; mi++) {
        int sr = wm + mi * 16 + l16;              // 0..127 in-tile s
        bf16x4 pk;
        pk[0] = (bf16)((acc[mi][ni][0] + bv4.x) * qscale);
        pk[1] = (bf16)((acc[mi][ni][1] + bv4.y) * qscale);
        pk[2] = (bf16)((acc[mi][ni][2] + bv4.z) * qscale);
        pk[3] = (bf16)((acc[mi][ni][3] + bv4.w) * qscale);
        int su = unit ^ (sr & 15);
        *(bf16x4*)(smem + sr * 128 + su * 8 + h8 * 4) = pk;
      }
    }
    __syncthreads();
    int sr = t >> 1, half = t & 1;
    int bb = mt >> 4;
    int s = ((mt & 15) << 7) + sr;
    int h = (nbase >> 6) + half;
    bf16* gout = outp + (((size_t)(bb * NH + h) * SQ + s) << 6);
#pragma unroll
    for (int i = 0; i < 8; i++) {
      int su = (half * 8 + i) ^ (sr & 15);
      bf16x8 ch = *(const bf16x8*)(smem + sr * 128 + su * 8);
      *(bf16x8*)(gout + i * 8) = ch;
    }
  } else {
    // V: [B,H,DH,S], s contiguous in r -> packed b64 stores
#pragma unroll
    for (int ni = 0; ni < 4; ni++) {
      int n = nbase + wn + ni * 16 + l16;
      int h = n >> 6, d = n & 63;
      float bv_ = bias[n];
#pragma unroll
      for (int mi = 0; mi < 4; mi++) {
        int m0 = mg0 + mi * 16 + quad * 4;
        int b = m0 >> 11, s = m0 & 2047;
        bf16x4 pk;
#pragma unroll
        for (int r = 0; r < 4; r++) pk[r] = (bf16)(acc[mi][ni][r] + bv_);
        *(bf16x4*)(outp + (((size_t)(b * NH + h) * HD + d) << 11) + s) = pk;
      }
    }
  }
}

// ---------------------------------------------------------------- attention
// 32x32x16 MFMA redesign: half the MFMA instructions at 4060 FLOP/issue-cyc
// (vs 3378 for 16x16x32). Per wave: one 32-q tile. S^T = mfma(K,Q) 32x32:
// C col=lane&31=q, row k=(r&3)+8*(r>>2)+4*hi (HW-verified layout). P->PV
// B-operand needs k=hi*8+e per lane: exactly 2 permlane32_swap per kpass
// (swap(u0,u2), swap(u1,u3) with the r3-verified vdst-high<->vsrc-low
// semantics). Staging/swizzle/loop identical to the 86us round-5 kernel.
// (Round 9 was an infra failure — container acquisition; kernel unchanged.)
__global__ __launch_bounds__(256, 4) void attn(
    const bf16* __restrict__ Q,     // [64][2048][64], pre-scaled by 0.125*log2e
    const bf16* __restrict__ K,     // [64][2048][64]
    const bf16* __restrict__ Vt,    // [64][64][2048]
    const float* __restrict__ mask, // [4][2048][2048]
    const int* __restrict__ flags,  // [4][16][32]
    float* __restrict__ out) {      // [4][2048][1024]
  __shared__ bf16 Ks[64 * 64];      // [s][d], chunk-swizzled
  __shared__ bf16 Vs[64 * 64];      // [d][s], chunk-swizzled

  int bh = blockIdx.x;              // 0..63
  int qt = blockIdx.y;
  int b = bh >> 4, h = bh & 15;
  int t = threadIdx.x, lane = t & 63, wid = t >> 6;
  int l32 = lane & 31, hi = lane >> 5;
  int q0 = qt * 128 + wid * 32;

  const bf16* Qp = Q + ((size_t)bh * SQ + q0) * HD;
  const bf16* Kp = K + (size_t)bh * SQ * HD;
  const bf16* Vp = Vt + (size_t)bh * HD * SQ;
  const float* mp = mask + ((size_t)b * SQ + q0) * SQ;
  const int* flg = flags + (b * 16 + qt) * 32;

  // Q B-frags [d 16][q 32]: lane l32 = q, d = dp*16 + hi*8 + e
  bf16x8 qa[4];
#pragma unroll
  for (int dp = 0; dp < 4; dp++)
    qa[dp] = *(const bf16x8*)(Qp + (size_t)l32 * HD + dp * 16 + hi * 8);

  floatx16 o2[2] = {};              // O^T: col=l32=q, row d = (r&3)+8*(r>>2)+4*hi + dt*32
  float li = 0.f;

  for (int kb = 0, kti = 0; kb < SQ; kb += 64, kti++) {
    __syncthreads();
#pragma unroll
    for (int p = 0; p < 2; p++) {
      int idx = p * 256 + t;        // 0..511
      int row = idx >> 3;
      int gch = (idx ^ row) & 7;
      ASYNC_COPY16(Kp + (size_t)(kb + row) * HD + gch * 8, Ks + idx * 8);
      ASYNC_COPY16(Vp + (size_t)row * SQ + kb + gch * 8, Vs + idx * 8);
    }
    __syncthreads();
    int flag = flg[kti];

    bf16x8 pf[2][2];
#pragma unroll
    for (int kt = 0; kt < 2; kt++) {
      // Phase A: S^T tile [32 k][32 q], contraction d=64 in 4 passes of 16
      int row = kt * 32 + l32;
      const bf16* kr = Ks + row * 64;
      floatx16 z = {};
      __builtin_amdgcn_s_setprio(1);
#pragma unroll
      for (int dp = 0; dp < 4; dp++) {
        int ch = (dp * 2 + hi) ^ (row & 7);
        bf16x8 kf = *(const bf16x8*)(kr + ch * 8);
        z = __builtin_amdgcn_mfma_f32_32x32x16_bf16(kf, qa[dp], z, 0, 0, 0);
      }
      __builtin_amdgcn_s_setprio(0);
      if (flag) {
#pragma unroll
        for (int r = 0; r < 16; r++) {
          int kk = kb + kt * 32 + (r & 3) + 8 * (r >> 2) + 4 * hi;
          z[r] = __builtin_fmaf(mp[(size_t)l32 * SQ + kk], LOG2E, z[r]);
        }
      }
      // Phase B: exp2 + sum; pack to bf16 pairs; permlane32 half-exchange
      float e[16];
      float s = 0.f;
#pragma unroll
      for (int r = 0; r < 16; r++) {
        e[r] = __builtin_amdgcn_exp2f(z[r]);
        s += e[r];
      }
      li += s;
#pragma unroll
      for (int kp = 0; kp < 2; kp++) {
        int bs = kp * 8;
        unsigned int u0, u1, u2, u3;
        asm("v_cvt_pk_bf16_f32 %0, %1, %2" : "=v"(u0) : "v"(e[bs + 0]), "v"(e[bs + 1]));
        asm("v_cvt_pk_bf16_f32 %0, %1, %2" : "=v"(u1) : "v"(e[bs + 2]), "v"(e[bs + 3]));
        asm("v_cvt_pk_bf16_f32 %0, %1, %2" : "=v"(u2) : "v"(e[bs + 4]), "v"(e[bs + 5]));
        asm("v_cvt_pk_bf16_f32 %0, %1, %2" : "=v"(u3) : "v"(e[bs + 6]), "v"(e[bs + 7]));
        // vdst-high <-> vsrc-low: u0=[u0_lo,u2_lo]->k{0,1}|{8,9}, u2=[u0_hi,u2_hi]->k{4,5}|{12,13}
        asm("v_permlane32_swap_b32 %0, %1" : "+v"(u0), "+v"(u2));
        asm("v_permlane32_swap_b32 %0, %1" : "+v"(u1), "+v"(u3));
        uint4t w;
        w[0] = u0; w[1] = u1; w[2] = u2; w[3] = u3;
        pf[kt][kp] = __builtin_bit_cast(bf16x8, w);
      }
    }

    // Phase C: O^T += V^T x P^T (2 dt tiles x 2 kt x 2 kpass)
    __builtin_amdgcn_s_setprio(1);
#pragma unroll
    for (int dt = 0; dt < 2; dt++) {
      int row = dt * 32 + l32;
      const bf16* vr = Vs + row * 64;
#pragma unroll
      for (int kt = 0; kt < 2; kt++)
#pragma unroll
        for (int kp = 0; kp < 2; kp++) {
          int ch = (kt * 4 + kp * 2 + hi) ^ (row & 7);
          bf16x8 vf = *(const bf16x8*)(vr + ch * 8);
          o2[dt] = __builtin_amdgcn_mfma_f32_32x32x16_bf16(vf, pf[kt][kp], o2[dt], 0, 0, 0);
        }
    }
    __builtin_amdgcn_s_setprio(0);
  }

  li += __shfl_xor(li, 32, 64);     // partner (same q, other hi) holds the other k-halves
  float inv = 1.0f / li;
  float* op = out + ((size_t)b * SQ + q0 + l32) * DMODEL + h * HD;
#pragma unroll
  for (int dt = 0; dt < 2; dt++)
#pragma unroll
    for (int g = 0; g < 4; g++) {
      float4 w;
      w.x = o2[dt][g * 4 + 0] * inv;
      w.y = o2[dt][g * 4 + 1] * inv;
      w.z = o2[dt][g * 4 + 2] * inv;
      w.w = o2[dt][g * 4 + 3] * inv;
      *(float4*)(op + dt * 32 + g * 8 + hi * 4) = w;
    }
}

// ---------------------------------------------------------------- launcher
extern "C" void kernel_launch(void* const* d_in, const int* in_sizes, int n_in,
                              void* d_out, int out_size, void* d_ws, size_t ws_size,
                              hipStream_t stream) {
  (void)in_sizes; (void)n_in; (void)out_size; (void)ws_size;
  const float* hs   = (const float*)d_in[0];
  const float* mask = (const float*)d_in[1];
  const float* Wq   = (const float*)d_in[2];
  const float* bq   = (const float*)d_in[3];
  const float* Wk   = (const float*)d_in[4];
  const float* bk   = (const float*)d_in[5];
  const float* Wv   = (const float*)d_in[6];
  const float* bv   = (const float*)d_in[7];
  float* out = (float*)d_out;
  char* ws = (char*)d_ws;
  bf16* xb = (bf16*)(ws + XB_OFF);
  bf16* wt = (bf16*)(ws + WT_OFF);
  bf16* q  = (bf16*)(ws + Q_OFF);
  bf16* k  = (bf16*)(ws + K_OFF);
  bf16* v  = (bf16*)(ws + V_OFF);
  int* flg = (int*)(ws + FLG_OFF);

  prep<<<1024 + 3072 + 2048, 256, 0, stream>>>(hs, xb, Wq, Wk, Wv, wt, mask, flg);
  qkv<<<1536, 256, 0, stream>>>(xb, wt, bq, bk, bv, q, k, v);
  attn<<<dim3(64, 16), 256, 0, stream>>>(q, k, v, mask, flg, out);
}

// Round 11
// 299.006 us; speedup vs baseline: 1.0023x; 1.0023x over previous
//
#include <hip/hip_runtime.h>

typedef __bf16 bf16;
typedef __bf16 bf16x8 __attribute__((ext_vector_type(8)));
typedef __bf16 bf16x4 __attribute__((ext_vector_type(4)));
typedef float floatx4 __attribute__((ext_vector_type(4)));
typedef float floatx16 __attribute__((ext_vector_type(16)));
typedef unsigned int uint4t __attribute__((ext_vector_type(4)));

typedef __attribute__((address_space(1))) void gvoid;
typedef __attribute__((address_space(3))) void lvoid;
#define ASYNC_COPY16(gp, lp) \
  __builtin_amdgcn_global_load_lds((gvoid*)(gp), (lvoid*)(lp), 16, 0, 0)

#define NB 4
#define SQ 2048
#define DMODEL 1024
#define NH 16
#define HD 64
#define MTOK (NB * SQ)   // 8192
#define LOG2E 1.44269504088896f

// workspace layout (bytes)
#define XB_OFF 0ull                        // bf16 X       [8192][1024]  16 MB
#define WT_OFF (16ull * 1024 * 1024)       // bf16 W^T x3  [3][1024][1024] 6 MB
#define Q_OFF  (22ull * 1024 * 1024)       // bf16 Q [64][2048][64]  16 MB (pre-scaled 0.125*log2e)
#define K_OFF  (38ull * 1024 * 1024)       // bf16 K [64][2048][64]  16 MB
#define V_OFF  (54ull * 1024 * 1024)       // bf16 V^T [64][64][2048] 16 MB
#define FLG_OFF (70ull * 1024 * 1024)      // int flags [4][16][32]   8 KB

// ------------------------------------------------- prep: convert X + transpose W + mask scan
// v3: W-transpose fat blocks — each block does a 32x128 strip (4 tiles, loads
// issued back-to-back before one barrier). 3072 latency-bound tiny blocks ->
// 768 ILP-rich ones (same fix that r4->r5 applied to the X branch).
// Grid: X 0..1023 | W 1024..1791 | mask 1792..3839.
__global__ __launch_bounds__(256) void prep(
    const float* __restrict__ x, bf16* __restrict__ xb,
    const float* __restrict__ w0, const float* __restrict__ w1,
    const float* __restrict__ w2, bf16* __restrict__ wt,
    const float* __restrict__ mask, int* __restrict__ flags) {
  __shared__ float t4[4][32][33];
  int blk = blockIdx.x;
  int t = threadIdx.x;
  if (blk < 1024) {
    // X: 8192x1024 f32 -> bf16. 8 float4/thread, coalesced.
    size_t base = (size_t)blk * 2048 + t;
    const float4* xin = (const float4*)x;
    bf16x4* xo = (bf16x4*)xb;
#pragma unroll
    for (int j = 0; j < 8; j++) {
      float4 v = xin[base + j * 256];
      bf16x4 o;
      o[0] = (bf16)v.x; o[1] = (bf16)v.y; o[2] = (bf16)v.z; o[3] = (bf16)v.w;
      xo[base + j * 256] = o;
    }
  } else if (blk < 1792) {
    int tidx = blk - 1024;            // 0..767
    int z = tidx >> 8;                // 0..2
    int rem = tidx & 255;
    int kbase = (rem >> 5) * 128;     // 0,128,..,896
    int nb = (rem & 31) * 32;
    const float* w = (z == 0) ? w0 : (z == 1) ? w1 : w2;
    bf16* out = wt + (size_t)z * DMODEL * DMODEL;
    int tx = t & 31, ty = t >> 5;     // 32 x 8
#pragma unroll
    for (int i4 = 0; i4 < 4; i4++) {
      int kb = kbase + i4 * 32;
#pragma unroll
      for (int i = 0; i < 4; i++)
        t4[i4][ty + 8 * i][tx] = w[(size_t)(kb + ty + 8 * i) * DMODEL + nb + tx];
    }
    __syncthreads();
#pragma unroll
    for (int i4 = 0; i4 < 4; i4++) {
      int kb = kbase + i4 * 32;
#pragma unroll
      for (int i = 0; i < 4; i++)
        out[(size_t)(nb + ty + 8 * i) * DMODEL + kb + tx] = (bf16)t4[i4][tx][ty + 8 * i];
    }
  } else {
    int midx = blk - 1792;            // 0..2047
    int kt = midx & 31, qt = (midx >> 5) & 15, b = midx >> 9;
    const float* mb = mask + ((size_t)b * SQ + qt * 128) * SQ + kt * 64;
    int row = t >> 1, half = t & 1;
    const float4* p = (const float4*)(mb + (size_t)row * SQ + half * 32);
    bool nz = false;
#pragma unroll
    for (int i = 0; i < 8; i++) {
      float4 vv = p[i];
      nz |= (vv.x != 0.f) | (vv.y != 0.f) | (vv.z != 0.f) | (vv.w != 0.f);
    }
    int* acc = (int*)t4;
    if (t == 0) acc[0] = 0;
    __syncthreads();
    unsigned long long m = __ballot(nz);
    if ((t & 63) == 0 && m) atomicOr(acc, 1);
    __syncthreads();
    if (t == 0) flags[(b * 16 + qt) * 32 + kt] = acc[0];
  }
}

// ---------------------------------------------------------------- QKV GEMM (pure)
// 1536 blocks = 64 mt x 24 nt; XCD band mapping (id&7 -> mt band) for L2 reuse.
#define BK 64
__global__ __launch_bounds__(256) void qkv(
    const bf16* __restrict__ xb,   // [8192][1024]
    const bf16* __restrict__ wt,   // [3][1024 n][1024 k]
    const float* __restrict__ biasq, const float* __restrict__ biask,
    const float* __restrict__ biasv,
    bf16* __restrict__ q, bf16* __restrict__ k, bf16* __restrict__ v) {
  __shared__ bf16 smem[2 * 128 * BK];   // As | Bs, reused as [128][128] epilogue stage
  bf16* As = smem;
  bf16* Bs = smem + 128 * BK;

  int id = blockIdx.x;              // 0..1535
  int local = id >> 3;              // 0..191
  int mt = ((id & 7) << 3) | (local & 7);  // 0..63, band per XCD
  int nt = local >> 3;              // 0..23
  int t = threadIdx.x;

  int mat = nt >> 3;                // 0=Q 1=K 2=V
  int nbase = (nt & 7) * 128;
  const bf16* wmat = wt + (size_t)mat * DMODEL * DMODEL;
  const float* bias = (mat == 0) ? biasq : (mat == 1) ? biask : biasv;
  bf16* outp = (mat == 0) ? q : (mat == 1) ? k : v;

  int lane = t & 63, wid = t >> 6;
  int quad = lane >> 4, l16 = lane & 15;
  int wm = (wid & 1) * 64, wn = (wid >> 1) * 64;
  int xq = quad ^ (l16 & 7);        // swizzled chunk index

  floatx4 acc[4][4] = {};

  for (int kb = 0; kb < DMODEL; kb += BK) {
    __syncthreads();
#pragma unroll
    for (int p = 0; p < 4; p++) {
      int i2 = p * 256 + t;
      int row = i2 >> 3;
      int gch = (i2 ^ row) & 7;
      ASYNC_COPY16(xb + (size_t)(mt * 128 + row) * DMODEL + kb + gch * 8,
                   As + i2 * 8);
      ASYNC_COPY16(wmat + (size_t)(nbase + row) * DMODEL + kb + gch * 8,
                   Bs + i2 * 8);
    }
    __syncthreads();

#pragma unroll
    for (int kc = 0; kc < BK; kc += 32) {
      int xc = (kc >> 3) ^ xq;
      bf16x8 af[4], bfr[4];
#pragma unroll
      for (int mi = 0; mi < 4; mi++)
        af[mi] = *(const bf16x8*)(As + (wm + mi * 16 + l16) * BK + xc * 8);
#pragma unroll
      for (int ni = 0; ni < 4; ni++)
        bfr[ni] = *(const bf16x8*)(Bs + (wn + ni * 16 + l16) * BK + xc * 8);
      if (mat < 2) {   // transposed: D[n][m], col=l16=token
#pragma unroll
        for (int mi = 0; mi < 4; mi++)
#pragma unroll
          for (int ni = 0; ni < 4; ni++)
            acc[mi][ni] = __builtin_amdgcn_mfma_f32_16x16x32_bf16(
                bfr[ni], af[mi], acc[mi][ni], 0, 0, 0);
      } else {         // normal: D[m][n], col=l16=feature
#pragma unroll
        for (int mi = 0; mi < 4; mi++)
#pragma unroll
          for (int ni = 0; ni < 4; ni++)
            acc[mi][ni] = __builtin_amdgcn_mfma_f32_16x16x32_bf16(
                af[mi], bfr[ni], acc[mi][ni], 0, 0, 0);
      }
    }
  }

  int mg0 = mt * 128 + wm;
  if (mat < 2) {
    // Q/K: stage [s 128][n 128] tile in LDS (16B-unit swizzle), coalesced out.
    float qscale = (mat == 0) ? 0.125f * LOG2E : 1.0f;
    __syncthreads();                    // all waves done reading As/Bs
#pragma unroll
    for (int ni = 0; ni < 4; ni++) {
      int n0 = nbase + wn + ni * 16 + quad * 4;
      float4 bv4 = *(const float4*)(bias + n0);
      int nc = wn + ni * 16 + quad * 4;           // 0..127 in-tile n
      int unit = nc >> 3, h8 = (nc >> 2) & 1;
#pragma unroll
      for (int mi = 0; mi < 4; mi++) {
        int sr = wm + mi * 16 + l16;              // 0..127 in-tile s
        bf16x4 pk;
        pk[0] = (bf16)((acc[mi][ni][0] + bv4.x) * qscale);
        pk[1] = (bf16)((acc[mi][ni][1] + bv4.y) * qscale);
        pk[2] = (bf16)((acc[mi][ni][2] + bv4.z) * qscale);
        pk[3] = (bf16)((acc[mi][ni][3] + bv4.w) * qscale);
        int su = unit ^ (sr & 15);
        *(bf16x4*)(smem + sr * 128 + su * 8 + h8 * 4) = pk;
      }
    }
    __syncthreads();
    int sr = t >> 1, half = t & 1;
    int bb = mt >> 4;
    int s = ((mt & 15) << 7) + sr;
    int h = (nbase >> 6) + half;
    bf16* gout = outp + (((size_t)(bb * NH + h) * SQ + s) << 6);
#pragma unroll
    for (int i = 0; i < 8; i++) {
      int su = (half * 8 + i) ^ (sr & 15);
      bf16x8 ch = *(const bf16x8*)(smem + sr * 128 + su * 8);
      *(bf16x8*)(gout + i * 8) = ch;
    }
  } else {
    // V: [B,H,DH,S], s contiguous in r -> packed b64 stores
#pragma unroll
    for (int ni = 0; ni < 4; ni++) {
      int n = nbase + wn + ni * 16 + l16;
      int h = n >> 6, d = n & 63;
      float bv_ = bias[n];
#pragma unroll
      for (int mi = 0; mi < 4; mi++) {
        int m0 = mg0 + mi * 16 + quad * 4;
        int b = m0 >> 11, s = m0 & 2047;
        bf16x4 pk;
#pragma unroll
        for (int r = 0; r < 4; r++) pk[r] = (bf16)(acc[mi][ni][r] + bv_);
        *(bf16x4*)(outp + (((size_t)(b * NH + h) * HD + d) << 11) + s) = pk;
      }
    }
  }
}

// ---------------------------------------------------------------- attention
// 32x32x16 MFMA structure (r10: 82.9us, 829 TF — near plain-HIP attn
// reference). S^T = mfma(K,Q): C col=lane&31=q, row k=(r&3)+8*(r>>2)+4*hi.
// P->PV B-operand via 2 permlane32_swap per kpass (verified). The 8.39M
// bank-conflict cycles (4/read) have no static explanation vs the
// conflict-free 16x16 pattern — left as-is (bounded, kernel still faster).
__global__ __launch_bounds__(256, 4) void attn(
    const bf16* __restrict__ Q,     // [64][2048][64], pre-scaled by 0.125*log2e
    const bf16* __restrict__ K,     // [64][2048][64]
    const bf16* __restrict__ Vt,    // [64][64][2048]
    const float* __restrict__ mask, // [4][2048][2048]
    const int* __restrict__ flags,  // [4][16][32]
    float* __restrict__ out) {      // [4][2048][1024]
  __shared__ bf16 Ks[64 * 64];      // [s][d], chunk-swizzled
  __shared__ bf16 Vs[64 * 64];      // [d][s], chunk-swizzled

  int bh = blockIdx.x;              // 0..63
  int qt = blockIdx.y;
  int b = bh >> 4, h = bh & 15;
  int t = threadIdx.x, lane = t & 63, wid = t >> 6;
  int l32 = lane & 31, hi = lane >> 5;
  int q0 = qt * 128 + wid * 32;

  const bf16* Qp = Q + ((size_t)bh * SQ + q0) * HD;
  const bf16* Kp = K + (size_t)bh * SQ * HD;
  const bf16* Vp = Vt + (size_t)bh * HD * SQ;
  const float* mp = mask + ((size_t)b * SQ + q0) * SQ;
  const int* flg = flags + (b * 16 + qt) * 32;

  // Q B-frags [d 16][q 32]: lane l32 = q, d = dp*16 + hi*8 + e
  bf16x8 qa[4];
#pragma unroll
  for (int dp = 0; dp < 4; dp++)
    qa[dp] = *(const bf16x8*)(Qp + (size_t)l32 * HD + dp * 16 + hi * 8);

  floatx16 o2[2] = {};              // O^T: col=l32=q, row d = (r&3)+8*(r>>2)+4*hi + dt*32
  float li = 0.f;

  for (int kb = 0, kti = 0; kb < SQ; kb += 64, kti++) {
    __syncthreads();
#pragma unroll
    for (int p = 0; p < 2; p++) {
      int idx = p * 256 + t;        // 0..511
      int row = idx >> 3;
      int gch = (idx ^ row) & 7;
      ASYNC_COPY16(Kp + (size_t)(kb + row) * HD + gch * 8, Ks + idx * 8);
      ASYNC_COPY16(Vp + (size_t)row * SQ + kb + gch * 8, Vs + idx * 8);
    }
    __syncthreads();
    int flag = flg[kti];

    bf16x8 pf[2][2];
#pragma unroll
    for (int kt = 0; kt < 2; kt++) {
      // Phase A: S^T tile [32 k][32 q], contraction d=64 in 4 passes of 16
      int row = kt * 32 + l32;
      const bf16* kr = Ks + row * 64;
      floatx16 z = {};
      __builtin_amdgcn_s_setprio(1);
#pragma unroll
      for (int dp = 0; dp < 4; dp++) {
        int ch = (dp * 2 + hi) ^ (row & 7);
        bf16x8 kf = *(const bf16x8*)(kr + ch * 8);
        z = __builtin_amdgcn_mfma_f32_32x32x16_bf16(kf, qa[dp], z, 0, 0, 0);
      }
      __builtin_amdgcn_s_setprio(0);
      if (flag) {
#pragma unroll
        for (int r = 0; r < 16; r++) {
          int kk = kb + kt * 32 + (r & 3) + 8 * (r >> 2) + 4 * hi;
          z[r] = __builtin_fmaf(mp[(size_t)l32 * SQ + kk], LOG2E, z[r]);
        }
      }
      // Phase B: exp2 + sum; pack to bf16 pairs; permlane32 half-exchange
      float e[16];
      float s = 0.f;
#pragma unroll
      for (int r = 0; r < 16; r++) {
        e[r] = __builtin_amdgcn_exp2f(z[r]);
        s += e[r];
      }
      li += s;
#pragma unroll
      for (int kp = 0; kp < 2; kp++) {
        int bs = kp * 8;
        unsigned int u0, u1, u2, u3;
        asm("v_cvt_pk_bf16_f32 %0, %1, %2" : "=v"(u0) : "v"(e[bs + 0]), "v"(e[bs + 1]));
        asm("v_cvt_pk_bf16_f32 %0, %1, %2" : "=v"(u1) : "v"(e[bs + 2]), "v"(e[bs + 3]));
        asm("v_cvt_pk_bf16_f32 %0, %1, %2" : "=v"(u2) : "v"(e[bs + 4]), "v"(e[bs + 5]));
        asm("v_cvt_pk_bf16_f32 %0, %1, %2" : "=v"(u3) : "v"(e[bs + 6]), "v"(e[bs + 7]));
        // vdst-high <-> vsrc-low: u0=[u0_lo,u2_lo]->k{0,1}|{8,9}, u2=[u0_hi,u2_hi]->k{4,5}|{12,13}
        asm("v_permlane32_swap_b32 %0, %1" : "+v"(u0), "+v"(u2));
        asm("v_permlane32_swap_b32 %0, %1" : "+v"(u1), "+v"(u3));
        uint4t w;
        w[0] = u0; w[1] = u1; w[2] = u2; w[3] = u3;
        pf[kt][kp] = __builtin_bit_cast(bf16x8, w);
      }
    }

    // Phase C: O^T += V^T x P^T (2 dt tiles x 2 kt x 2 kpass)
    __builtin_amdgcn_s_setprio(1);
#pragma unroll
    for (int dt = 0; dt < 2; dt++) {
      int row = dt * 32 + l32;
      const bf16* vr = Vs + row * 64;
#pragma unroll
      for (int kt = 0; kt < 2; kt++)
#pragma unroll
        for (int kp = 0; kp < 2; kp++) {
          int ch = (kt * 4 + kp * 2 + hi) ^ (row & 7);
          bf16x8 vf = *(const bf16x8*)(vr + ch * 8);
          o2[dt] = __builtin_amdgcn_mfma_f32_32x32x16_bf16(vf, pf[kt][kp], o2[dt], 0, 0, 0);
        }
    }
    __builtin_amdgcn_s_setprio(0);
  }

  li += __shfl_xor(li, 32, 64);     // partner (same q, other hi) holds the other k-halves
  float inv = 1.0f / li;
  float* op = out + ((size_t)b * SQ + q0 + l32) * DMODEL + h * HD;
#pragma unroll
  for (int dt = 0; dt < 2; dt++)
#pragma unroll
    for (int g = 0; g < 4; g++) {
      float4 w;
      w.x = o2[dt][g * 4 + 0] * inv;
      w.y = o2[dt][g * 4 + 1] * inv;
      w.z = o2[dt][g * 4 + 2] * inv;
      w.w = o2[dt][g * 4 + 3] * inv;
      *(float4*)(op + dt * 32 + g * 8 + hi * 4) = w;
    }
}

// ---------------------------------------------------------------- launcher
extern "C" void kernel_launch(void* const* d_in, const int* in_sizes, int n_in,
                              void* d_out, int out_size, void* d_ws, size_t ws_size,
                              hipStream_t stream) {
  (void)in_sizes; (void)n_in; (void)out_size; (void)ws_size;
  const float* hs   = (const float*)d_in[0];
  const float* mask = (const float*)d_in[1];
  const float* Wq   = (const float*)d_in[2];
  const float* bq   = (const float*)d_in[3];
  const float* Wk   = (const float*)d_in[4];
  const float* bk   = (const float*)d_in[5];
  const float* Wv   = (const float*)d_in[6];
  const float* bv   = (const float*)d_in[7];
  float* out = (float*)d_out;
  char* ws = (char*)d_ws;
  bf16* xb = (bf16*)(ws + XB_OFF);
  bf16* wt = (bf16*)(ws + WT_OFF);
  bf16* q  = (bf16*)(ws + Q_OFF);
  bf16* k  = (bf16*)(ws + K_OFF);
  bf16* v  = (bf16*)(ws + V_OFF);
  int* flg = (int*)(ws + FLG_OFF);

  prep<<<1024 + 768 + 2048, 256, 0, stream>>>(hs, xb, Wq, Wk, Wv, wt, mask, flg);
  qkv<<<1536, 256, 0, stream>>>(xb, wt, bq, bk, bv, q, k, v);
  attn<<<dim3(64, 16), 256, 0, stream>>>(q, k, v, mask, flg, out);
}